// Round 13
// baseline (120.005 us; speedup 1.0000x reference)
//
#include <hip/hip_runtime.h>
#include <math.h>

#define B_ 64
#define C_ 8
#define T_ 2048
#define NF_ 32
#define MLP_ 32
#define HID_ 64
#define W_ 1985
#define CH_ 32
#define NCHUNK_ 63   /* ceil(1985/32) */
#define PI_F 3.14159265358979323846f

typedef _Float16 f16x8 __attribute__((ext_vector_type(8)));
typedef _Float16 f16x2 __attribute__((ext_vector_type(2)));
typedef float    f32x4 __attribute__((ext_vector_type(4)));

// ws layout (floats):
// [0..1] stats | [64..4095] partial | [4096..6143] twHi | [6144..8191] twLo |
// [8192..16383] pwHi (16384 f16) | [16384..24575] pwLo |
// [24576..25599] w0Hi | [25600..26623] w0Lo | [26624..27647] w1Hi | [27648..28671] w1Lo
#define WS_PARTIAL 64
#define WS_TWHI    4096
#define WS_TWLO    6144
#define WS_PWHI    8192
#define WS_PWLO    16384
#define WS_W0HI    24576
#define WS_W0LO    25600
#define WS_W1HI    26624
#define WS_W1LO    27648

// ---------------- fast inline transcendentals (branchless) ----------------
__device__ __forceinline__ float fast_rcp(float x) { return __builtin_amdgcn_rcpf(x); }

__device__ __forceinline__ float fast_atan2pi(float y, float x)
{
    const float ax = fabsf(x), ay = fabsf(y);
    const float mx = fmaxf(ax, ay), mn = fminf(ax, ay);
    const float r  = mn * fast_rcp(fmaxf(mx, 1e-30f));
    const float t  = r * r;
    float a = -0.003730950f;
    a = fmaf(a, t,  0.016759940f);
    a = fmaf(a, t, -0.037059946f);
    a = fmaf(a, t,  0.061602941f);
    a = fmaf(a, t, -0.105877528f);
    a = fmaf(a, t,  0.318302656f);
    a *= r;
    a = (ay > ax) ? (0.5f - a) : a;
    a = (x < 0.0f) ? (1.0f - a) : a;
    return copysignf(a, y);
}

__device__ __forceinline__ float fast_tanh(float x)
{
    const float e = __expf(2.0f * x);
    return 1.0f - 2.0f * fast_rcp(e + 1.0f);
}

__device__ __forceinline__ float fast_snake(float h, float rcp_aa, float aa)
{
    const float s = __sinf(aa * h);
    return h + s * s * rcp_aa;
}

__device__ __forceinline__ float dot4(float4 a, float4 b, float acc)
{
    return fmaf(a.x, b.x, fmaf(a.y, b.y, fmaf(a.z, b.z, fmaf(a.w, b.w, acc))));
}

// pack f32 -> (f16 hi, f16 lo) in one u32 (hi in low 16 bits)
__device__ __forceinline__ unsigned packhl(float v)
{
    const _Float16 h = (_Float16)v;
    const _Float16 l = (_Float16)(v - (float)h);
    f16x2 p; p[0] = h; p[1] = l;
    return __builtin_bit_cast(unsigned, p);
}

// from 8 packed u32 (ascending k) build hi-f16x8 and lo-f16x8 via v_perm
__device__ __forceinline__ void unpack8(const unsigned* u, f16x8& ah, f16x8& al)
{
    union { unsigned w[4]; f16x8 v; } H, L;
    #pragma unroll
    for (int j = 0; j < 4; ++j) {
        H.w[j] = __builtin_amdgcn_perm(u[2*j+1], u[2*j], 0x05040100u);
        L.w[j] = __builtin_amdgcn_perm(u[2*j+1], u[2*j], 0x07060302u);
    }
    ah = H.v; al = L.v;
}

// async global->LDS, 16B per lane (dest linear in lane, proven r6-r12 pattern)
__device__ __forceinline__ void gload_lds16(const void* g, void* l)
{
    __builtin_amdgcn_global_load_lds(
        (const __attribute__((address_space(1))) void*)g,
        (__attribute__((address_space(3))) void*)l, 16, 0, 0);
}

// ---------------------------------------------------------------------------
// K1 (grid 8): work-split across blocks:
//   all blocks: own pw slice (2048 elems) -> hi/lo planes
//   block 0: twiddle tables (fast __sincosf)
//   block 1: w0/w1 hi/lo planes
//   block 2: softmax stats
// ---------------------------------------------------------------------------
__global__ __launch_bounds__(1024) void k_pre(
    const float* __restrict__ agg, const float* __restrict__ pw,
    const float* __restrict__ w0g, const float* __restrict__ w1g,
    float* __restrict__ ws)
{
    __shared__ float red[1024];
    const int t   = threadIdx.x;
    const int blk = blockIdx.x;

    // pw slice for this block
    _Float16* pwHi = (_Float16*)(ws + WS_PWHI);
    _Float16* pwLo = (_Float16*)(ws + WS_PWLO);
    #pragma unroll
    for (int e = 0; e < 2; ++e) {
        const int id = blk * 2048 + e * 1024 + t;   // 0..16383
        const float v = pw[id];
        const _Float16 h = (_Float16)v;
        pwHi[id] = h;
        pwLo[id] = (_Float16)(v - (float)h);
    }

    if (blk == 0) {
        _Float16* twHi = (_Float16*)(ws + WS_TWHI);
        _Float16* twLo = (_Float16*)(ws + WS_TWLO);
        #pragma unroll
        for (int e = 0; e < 4; ++e) {
            const int id = t * 4 + e;          // 0..4095
            const int n = id >> 6, k = id & 63;
            const int f = n & 31;
            float s, c;
            __sincosf(0.0981747704246810387f * (float)((k * f) & 63), &s, &c);
            const float v = (n < 32) ? c : -s;
            const _Float16 h = (_Float16)v;
            twHi[id] = h;
            twLo[id] = (_Float16)(v - (float)h);
        }
    } else if (blk == 1) {
        _Float16* w0Hi = (_Float16*)(ws + WS_W0HI);
        _Float16* w0Lo = (_Float16*)(ws + WS_W0LO);
        _Float16* w1Hi = (_Float16*)(ws + WS_W1HI);
        _Float16* w1Lo = (_Float16*)(ws + WS_W1LO);
        #pragma unroll
        for (int e = 0; e < 2; ++e) {
            const int id = e * 1024 + t;       // 0..2047
            const float v0 = w0g[id];
            const _Float16 h0 = (_Float16)v0;
            w0Hi[id] = h0;
            w0Lo[id] = (_Float16)(v0 - (float)h0);
            const float v1 = w1g[id];
            const _Float16 h1 = (_Float16)v1;
            w1Hi[id] = h1;
            w1Lo[id] = (_Float16)(v1 - (float)h1);
        }
    } else if (blk == 2) {
        float m = -1e30f;
        for (int i = t; i < W_; i += 1024) m = fmaxf(m, agg[i]);
        red[t] = m;
        __syncthreads();
        for (int s = 512; s > 0; s >>= 1) {
            if (t < s) red[t] = fmaxf(red[t], red[t + s]);
            __syncthreads();
        }
        const float mx = red[0];
        __syncthreads();
        float sum = 0.f;
        for (int i = t; i < W_; i += 1024) sum += __expf(agg[i] - mx);
        red[t] = sum;
        __syncthreads();
        for (int s = 512; s > 0; s >>= 1) {
            if (t < s) red[t] += red[t + s];
            __syncthreads();
        }
        if (t == 0) { ws[0] = mx; ws[1] = red[0]; }
    }
}

// ---------------------------------------------------------------------------
// K2: DFT-MFMA -> mag/ph (pass-0 pw async-staged to LDS underneath; pass-1 B
//     prefetched to regs) -> proj GEMM -> MFMA h0/h1 -> out.
//     1024 thr, ~67 KB LDS -> 2 blocks/CU.
// ---------------------------------------------------------------------------
__global__ __launch_bounds__(1024, 8) void k_main(
    const float* __restrict__ x,  const float* __restrict__ pw,
    const float* __restrict__ pb, const float* __restrict__ w0g,
    const float* __restrict__ b0g,const float* __restrict__ a0g,
    const float* __restrict__ w1g,const float* __restrict__ b1g,
    const float* __restrict__ a1g,const float* __restrict__ wog,
    const float* __restrict__ bog,const float* __restrict__ agg,
    const float* __restrict__ wsp, float* __restrict__ partial)
{
    __shared__ __align__(16) _Float16 featP[16384];    // 32768 B
    __shared__ __align__(16) _Float16 arena2[16384];   // 32768 B
    __shared__ float smalls[260];
    __shared__ float chunkAcc[CH_];
    // total ~67 KB -> 2 blocks/CU

    _Float16* featHi = featP;               // [32][256]
    _Float16* featLo = featP + 8192;
    // arena2 phase 1: twiddle planes + packed xtile; phase 2: pass-0 pw planes
    _Float16* twHiL  = arena2;              // [64][64] swizzled granules
    _Float16* twLoL  = arena2 + 4096;
    unsigned* xtileP = (unsigned*)(arena2 + 8192);  // [8][100] packed hi|lo
    _Float16* pw0Hi  = arena2;              // [32][256] swizzled (after DFT)
    _Float16* pw0Lo  = arena2 + 8192;
    // overlays inside featP (disjoint live ranges, barriers between):
    float*    pacc   = (float*)featP;       // [4][32][33] = 4224 f, bytes [0..16896)
    _Float16* projHi = featP + 8448;        // [32][40], bytes [16896..19456)
    _Float16* projLo = featP + 8448 + 1280; // bytes [19456..22016)
    _Float16* h0Hi   = featP + 11008;       // [32][72], bytes [22016..26624)
    _Float16* h0Lo   = featP + 11008 + 2304;// bytes [26624..31232)
    float*    h1L    = (float*)featP;       // [32][36], bytes [0..4608) after pacc dead

    const int t     = threadIdx.x;
    const int chunk = blockIdx.x;
    const int b     = blockIdx.y;
    const int w0c   = chunk * CH_;
    const int wid   = t >> 6;
    const int lane  = t & 63;
    const int m16   = lane & 15;
    const int kl    = lane >> 4;
    const int cdft  = wid >> 1;             // DFT channel 0..7

    // ---- async twiddle -> LDS (pre-swizzled source, r8-r12 pattern) ----
    {
        const int gl = (wid & 7) * 64 + lane;      // granule 0..511
        const int n  = gl >> 3, q = gl & 7;
        const int srcg = n * 8 + (q ^ (n & 7));
        const float* srcbase = wsp + ((wid < 8) ? WS_TWHI : WS_TWLO);
        _Float16* dst = ((wid < 8) ? twHiL : twLoL) + gl * 8;
        gload_lds16((const char*)srcbase + srcg * 16, dst);
    }

    // ---- stage x tile (packed), smalls ----
    if (t < C_ * 96) {
        const int c = t / 96;
        const int j = t - c * 96;
        int gi = w0c + j; if (gi > T_ - 1) gi = T_ - 1;
        xtileP[c * 100 + j] = packhl(x[((size_t)b * C_ + c) * T_ + gi]);
    }
    if (t < 257) {
        float smv;
        if      (t <  32) smv = pb[t];
        else if (t <  96) smv = b0g[t - 32];
        else if (t < 160) smv = a0g[t - 96];
        else if (t < 192) smv = b1g[t - 160];
        else if (t < 224) smv = a1g[t - 192];
        else if (t < 256) smv = wog[t - 224];
        else              smv = bog[0];
        smalls[t] = smv;
    }
    __syncthreads();   // xtile/smalls ready; twiddle drained (barrier=vmcnt0)

    // GEMM slot ids (used for prefetch + GEMM)
    const int gwt = (wid >> 1) & 1;
    const int got = wid & 1;
    const int gkq = wid >> 2;
    const int garow = gwt * 16 + m16;
    const int gbrow = got * 16 + m16;

    // ---- DFT-MFMA: A built in-reg from xtileP (perm), B twiddle planes ----
    f32x4 dacc0 = {0.f,0.f,0.f,0.f}, dacc1 = {0.f,0.f,0.f,0.f};
    f32x4 dacc2 = {0.f,0.f,0.f,0.f}, dacc3 = {0.f,0.f,0.f,0.f};
    const int wra = (wid & 1) * 16 + m16;   // A-row's window index w
    {
        #pragma unroll
        for (int kstep = 0; kstep < 2; ++kstep) {
            const int kq = kstep * 4 + kl;
            unsigned ut[8];
            #pragma unroll
            for (int j = 0; j < 8; ++j) ut[j] = xtileP[cdft * 100 + wra + kq * 8 + j];
            f16x8 ah, al; unpack8(ut, ah, al);
            __builtin_amdgcn_s_setprio(1);
            #define DFT_NT(dn, NT) { \
                const int nrow = (NT) * 16 + m16; \
                const int gB = (nrow * 8 + (kq ^ (nrow & 7))) * 8; \
                const f16x8 bh = *(const f16x8*)&twHiL[gB]; \
                const f16x8 bl = *(const f16x8*)&twLoL[gB]; \
                dn = __builtin_amdgcn_mfma_f32_16x16x32_f16(ah, bh, dn, 0, 0, 0); \
                dn = __builtin_amdgcn_mfma_f32_16x16x32_f16(al, bh, dn, 0, 0, 0); \
                dn = __builtin_amdgcn_mfma_f32_16x16x32_f16(ah, bl, dn, 0, 0, 0); }
            DFT_NT(dacc0, 0)
            DFT_NT(dacc1, 1)
            DFT_NT(dacc2, 2)
            DFT_NT(dacc3, 3)
            #undef DFT_NT
            __builtin_amdgcn_s_setprio(0);
        }
    }
    __syncthreads();   // twiddle/xtile reads complete -> arena2 reusable

    // ---- issue pass-0 pw planes -> arena2 (async; latency hides under mag/ph)
    {
        const char* pwbytes = (const char*)wsp;
        #pragma unroll
        for (int r = 0; r < 2; ++r) {
            const int gw = (r * 16 + wid) * 64;    // wave-uniform granule base
            const int g  = gw + lane;              // dest linear in lane
            const int plane = g >> 10;
            const int gp = g & 1023;
            const int o  = gp >> 5;
            const int q  = gp & 31;
            const size_t srcoff = (size_t)(plane ? WS_PWLO : WS_PWHI) * 4
                                + (size_t)o * 1024 + (size_t)((q ^ (o & 7)) * 16);
            gload_lds16(pwbytes + srcoff, (char*)arena2 + (size_t)g * 16);
        }
    }

    // ---- prefetch pass-1 B into registers (latency hides under mag/ph) ----
    const _Float16* pwHi = (const _Float16*)(wsp + WS_PWHI);
    const _Float16* pwLo = (const _Float16*)(wsp + WS_PWLO);
    f16x8 b1h[2], b1l[2];
    #pragma unroll
    for (int kstep = 0; kstep < 2; ++kstep) {
        const int kp = gkq * 64 + kstep * 32 + kl * 8;
        b1h[kstep] = *(const f16x8*)&pwHi[(size_t)gbrow * 512 + 256 + kp];
        b1l[kstep] = *(const f16x8*)&pwLo[(size_t)gbrow * 512 + 256 + kp];
    }

    // ---- mag/ph (all waves); waves 0-7 write feat planes (c0-3), 8-15 hold --
    unsigned heldHi[2][4], heldLo[2][4];
    {
        const int wbase = (wid & 1) * 16 + kl * 4;
        const int ccl   = cdft & 3;
        const float reA[2][4] = {{dacc0[0],dacc0[1],dacc0[2],dacc0[3]},
                                 {dacc1[0],dacc1[1],dacc1[2],dacc1[3]}};
        const float imA[2][4] = {{dacc2[0],dacc2[1],dacc2[2],dacc2[3]},
                                 {dacc3[0],dacc3[1],dacc3[2],dacc3[3]}};
        #pragma unroll
        for (int fi = 0; fi < 2; ++fi) {
            const int f = fi * 16 + m16;
            const int g = ccl * 8 + (f >> 2);
            const int sub = 2 * (f & 3);
            #pragma unroll
            for (int r = 0; r < 4; ++r) {
                const int w  = wbase + r;
                const float re = reA[fi][r], im = imA[fi][r];
                const float mag = __logf(1.0f + __builtin_amdgcn_sqrtf(re*re + im*im));
                const float ph  = fast_atan2pi(im, re);
                const _Float16 mh = (_Float16)mag;
                const _Float16 qh = (_Float16)ph;
                f16x2 vh; vh[0] = mh; vh[1] = qh;
                f16x2 vl;
                vl[0] = (_Float16)(mag - (float)mh);
                vl[1] = (_Float16)(ph  - (float)qh);
                if (wid < 8) {
                    const int off = w * 256 + ((g ^ (w & 7)) * 8) + sub;
                    *(f16x2*)&featHi[off] = vh;
                    *(f16x2*)&featLo[off] = vl;
                } else {
                    heldHi[fi][r] = __builtin_bit_cast(unsigned, vh);
                    heldLo[fi][r] = __builtin_bit_cast(unsigned, vl);
                }
            }
        }
    }
    __syncthreads();   // feat pass-0 ready; pw0 planes drained (vmcnt0)

    // ---- proj GEMM: K-split 2; pass0 B from LDS, pass1 B from regs ----
    {
        f32x4 acc = {0.f, 0.f, 0.f, 0.f};
        #pragma unroll
        for (int p = 0; p < 2; ++p) {
            __builtin_amdgcn_s_setprio(1);
            #pragma unroll
            for (int kstep = 0; kstep < 2; ++kstep) {
                const int kp = gkq * 64 + kstep * 32 + kl * 8;   // local k'
                f16x8 bh, bl;
                if (p == 0) {
                    const int offB = gbrow * 256 + (((kp >> 3) ^ (gbrow & 7)) * 8);
                    bh = *(const f16x8*)&pw0Hi[offB];
                    bl = *(const f16x8*)&pw0Lo[offB];
                } else {
                    bh = b1h[kstep];
                    bl = b1l[kstep];
                }
                const int g0 = kp >> 3;
                const int offA = garow * 256 + ((g0 ^ (garow & 7)) * 8);
                const f16x8 ah = *(const f16x8*)&featHi[offA];
                const f16x8 al = *(const f16x8*)&featLo[offA];
                acc = __builtin_amdgcn_mfma_f32_16x16x32_f16(ah, bh, acc, 0, 0, 0);
                acc = __builtin_amdgcn_mfma_f32_16x16x32_f16(al, bh, acc, 0, 0, 0);
                acc = __builtin_amdgcn_mfma_f32_16x16x32_f16(ah, bl, acc, 0, 0, 0);
            }
            __builtin_amdgcn_s_setprio(0);
            if (p == 0) {
                __syncthreads();      // pass-0 feat reads done
                if (wid >= 8) {       // waves 8-15: write c4-7 features
                    const int wbase = (wid & 1) * 16 + kl * 4;
                    const int ccl   = cdft & 3;
                    #pragma unroll
                    for (int fi = 0; fi < 2; ++fi) {
                        const int f = fi * 16 + m16;
                        const int g = ccl * 8 + (f >> 2);
                        const int sub = 2 * (f & 3);
                        #pragma unroll
                        for (int r = 0; r < 4; ++r) {
                            const int w  = wbase + r;
                            const int off = w * 256 + ((g ^ (w & 7)) * 8) + sub;
                            *(unsigned*)&featHi[off] = heldHi[fi][r];
                            *(unsigned*)&featLo[off] = heldLo[fi][r];
                        }
                    }
                }
                __syncthreads();
            }
        }
        __syncthreads();   // pass-1 feat reads done; region free for pacc
        #pragma unroll
        for (int r = 0; r < 4; ++r) {
            const int w = gwt * 16 + kl * 4 + r;
            const int o = got * 16 + m16;
            pacc[gkq * 1056 + w * 33 + o] = acc[r];
        }
    }
    __syncthreads();

    // ---- finalize proj: reduce 4 kq partials, bias, tanh -> proj planes ----
    {
        const int o = t & 31;
        const int w = t >> 5;
        float s = smalls[o];
        #pragma unroll
        for (int q = 0; q < 4; ++q) s += pacc[q * 1056 + w * 33 + o];
        const float pr = fast_tanh(s) * PI_F;
        const _Float16 h = (_Float16)pr;
        projHi[w * 40 + o] = h;
        projLo[w * 40 + o] = (_Float16)(pr - (float)h);
    }
    __syncthreads();

    // ---- h0 = snake(proj @ w0^T + b0) via MFMA: 8 waves, 3 MFMA each ----
    const _Float16* w0Hi = (const _Float16*)(wsp + WS_W0HI);
    const _Float16* w0Lo = (const _Float16*)(wsp + WS_W0LO);
    if (wid < 8) {
        const int wt = wid & 1;
        const int ot = wid >> 1;          // 0..3
        const int arow = wt * 16 + m16;   // proj row w
        const int brow = ot * 16 + m16;   // h0 output o
        const f16x8 ah = *(const f16x8*)&projHi[arow * 40 + kl * 8];
        const f16x8 al = *(const f16x8*)&projLo[arow * 40 + kl * 8];
        const f16x8 bh = *(const f16x8*)&w0Hi[brow * 32 + kl * 8];
        const f16x8 bl = *(const f16x8*)&w0Lo[brow * 32 + kl * 8];
        f32x4 acc = {0.f, 0.f, 0.f, 0.f};
        acc = __builtin_amdgcn_mfma_f32_16x16x32_f16(ah, bh, acc, 0, 0, 0);
        acc = __builtin_amdgcn_mfma_f32_16x16x32_f16(al, bh, acc, 0, 0, 0);
        acc = __builtin_amdgcn_mfma_f32_16x16x32_f16(ah, bl, acc, 0, 0, 0);
        const int o  = ot * 16 + m16;
        const float b0v = smalls[32 + o];
        const float aa  = fabsf(smalls[96 + o]) + 1e-8f;
        const float ra  = fast_rcp(aa);
        #pragma unroll
        for (int r = 0; r < 4; ++r) {
            const int w = wt * 16 + kl * 4 + r;
            const float hv = fast_snake(acc[r] + b0v, ra, aa);
            const _Float16 h = (_Float16)hv;
            h0Hi[w * 72 + o] = h;
            h0Lo[w * 72 + o] = (_Float16)(hv - (float)h);
        }
    }
    __syncthreads();

    // ---- h1 = snake(h0 @ w1^T + b1) via MFMA: 4 waves, 6 MFMA each ----
    const _Float16* w1Hi = (const _Float16*)(wsp + WS_W1HI);
    const _Float16* w1Lo = (const _Float16*)(wsp + WS_W1LO);
    if (wid < 4) {
        const int wt = wid & 1;
        const int ot = wid >> 1;          // 0..1
        const int arow = wt * 16 + m16;   // h0 row w
        const int brow = ot * 16 + m16;   // h1 output o
        f32x4 acc = {0.f, 0.f, 0.f, 0.f};
        #pragma unroll
        for (int ks = 0; ks < 2; ++ks) {
            const f16x8 ah = *(const f16x8*)&h0Hi[arow * 72 + ks * 32 + kl * 8];
            const f16x8 al = *(const f16x8*)&h0Lo[arow * 72 + ks * 32 + kl * 8];
            const f16x8 bh = *(const f16x8*)&w1Hi[brow * 64 + ks * 32 + kl * 8];
            const f16x8 bl = *(const f16x8*)&w1Lo[brow * 64 + ks * 32 + kl * 8];
            acc = __builtin_amdgcn_mfma_f32_16x16x32_f16(ah, bh, acc, 0, 0, 0);
            acc = __builtin_amdgcn_mfma_f32_16x16x32_f16(al, bh, acc, 0, 0, 0);
            acc = __builtin_amdgcn_mfma_f32_16x16x32_f16(ah, bl, acc, 0, 0, 0);
        }
        const int o  = ot * 16 + m16;
        const float b1v = smalls[160 + o];
        const float aa  = fabsf(smalls[192 + o]) + 1e-8f;
        const float ra  = fast_rcp(aa);
        #pragma unroll
        for (int r = 0; r < 4; ++r) {
            const int w = wt * 16 + kl * 4 + r;
            h1L[w * 36 + o] = fast_snake(acc[r] + b1v, ra, aa);
        }
    }
    __syncthreads();

    // ---- out_t + softmax weight ----
    if (t < CH_) {
        const int w = t;
        float acc = 0.f;
        #pragma unroll
        for (int q = 0; q < 8; ++q)
            acc = dot4(*(const float4*)&h1L[w * 36 + q * 4],
                       *(const float4*)&smalls[224 + q * 4], acc);
        const float val = acc + smalls[256];
        const int wg = w0c + w;
        const float sw = (wg < W_) ? __expf(agg[wg] - wsp[0]) / wsp[1] : 0.f;
        chunkAcc[w] = val * sw;
    }
    __syncthreads();

    // ---- reduce 32 chunk values -> 1 partial ----
    if (t < 32) {
        float vs = chunkAcc[t];
        vs += __shfl_down(vs, 16);
        vs += __shfl_down(vs, 8);
        vs += __shfl_down(vs, 4);
        vs += __shfl_down(vs, 2);
        vs += __shfl_down(vs, 1);
        if (t == 0) partial[(size_t)chunk * B_ + b] = vs;
    }
}

// ---------------------------------------------------------------------------
// K3: final reduce over chunks -> d_out[b]. 1024 thr: 16 lanes per b.
// ---------------------------------------------------------------------------
__global__ __launch_bounds__(1024) void k_reduce(
    const float* __restrict__ partial, float* __restrict__ out)
{
    const int t = threadIdx.x;
    const int b = t >> 4;
    const int j = t & 15;
    float s = 0.f;
    #pragma unroll
    for (int q = 0; q < 4; ++q) {
        const int c = j + q * 16;
        if (c < NCHUNK_) s += partial[(size_t)c * B_ + b];
    }
    s += __shfl_xor(s, 8, 16);
    s += __shfl_xor(s, 4, 16);
    s += __shfl_xor(s, 2, 16);
    s += __shfl_xor(s, 1, 16);
    if (j == 0) out[b] = s;
}

// ---------------------------------------------------------------------------
extern "C" void kernel_launch(void* const* d_in, const int* in_sizes, int n_in,
                              void* d_out, int out_size, void* d_ws, size_t ws_size,
                              hipStream_t stream)
{
    const float* x   = (const float*)d_in[0];
    const float* pw  = (const float*)d_in[1];
    const float* pb  = (const float*)d_in[2];
    const float* w0  = (const float*)d_in[3];
    const float* b0  = (const float*)d_in[4];
    const float* a0  = (const float*)d_in[5];
    const float* w1  = (const float*)d_in[6];
    const float* b1  = (const float*)d_in[7];
    const float* a1  = (const float*)d_in[8];
    const float* wo  = (const float*)d_in[9];
    const float* bo  = (const float*)d_in[10];
    const float* agg = (const float*)d_in[11];
    float* ws  = (float*)d_ws;
    float* out = (float*)d_out;

    k_pre<<<8, 1024, 0, stream>>>(agg, pw, w0, w1, ws);
    dim3 grid(NCHUNK_, B_);
    k_main<<<grid, 1024, 0, stream>>>(x, pw, pb, w0, b0, a0, w1, b1, a1, wo, bo,
                                      agg, ws, ws + WS_PARTIAL);
    k_reduce<<<1, 1024, 0, stream>>>(ws + WS_PARTIAL, out);
}

// Round 14
// 112.130 us; speedup vs baseline: 1.0702x; 1.0702x over previous
//
#include <hip/hip_runtime.h>
#include <math.h>

#define B_ 64
#define C_ 8
#define T_ 2048
#define NF_ 32
#define MLP_ 32
#define HID_ 64
#define W_ 1985
#define CH_ 32
#define NCHUNK_ 63   /* ceil(1985/32) */
#define PI_F 3.14159265358979323846f

typedef _Float16 f16x8 __attribute__((ext_vector_type(8)));
typedef _Float16 f16x2 __attribute__((ext_vector_type(2)));
typedef float    f32x4 __attribute__((ext_vector_type(4)));

// ws layout (floats):
// [0..1] stats | [64..4095] partial | [4096..6143] twHi | [6144..8191] twLo |
// [8192..16383] pwHi (16384 f16) | [16384..24575] pwLo |
// [24576..25599] w0Hi | [25600..26623] w0Lo | [26624..27647] w1Hi | [27648..28671] w1Lo
#define WS_PARTIAL 64
#define WS_TWHI    4096
#define WS_TWLO    6144
#define WS_PWHI    8192
#define WS_PWLO    16384
#define WS_W0HI    24576
#define WS_W0LO    25600
#define WS_W1HI    26624
#define WS_W1LO    27648

// ---------------- fast inline transcendentals (branchless) ----------------
__device__ __forceinline__ float fast_rcp(float x) { return __builtin_amdgcn_rcpf(x); }

__device__ __forceinline__ float fast_atan2pi(float y, float x)
{
    const float ax = fabsf(x), ay = fabsf(y);
    const float mx = fmaxf(ax, ay), mn = fminf(ax, ay);
    const float r  = mn * fast_rcp(fmaxf(mx, 1e-30f));
    const float t  = r * r;
    float a = -0.003730950f;
    a = fmaf(a, t,  0.016759940f);
    a = fmaf(a, t, -0.037059946f);
    a = fmaf(a, t,  0.061602941f);
    a = fmaf(a, t, -0.105877528f);
    a = fmaf(a, t,  0.318302656f);
    a *= r;
    a = (ay > ax) ? (0.5f - a) : a;
    a = (x < 0.0f) ? (1.0f - a) : a;
    return copysignf(a, y);
}

__device__ __forceinline__ float fast_tanh(float x)
{
    const float e = __expf(2.0f * x);
    return 1.0f - 2.0f * fast_rcp(e + 1.0f);
}

__device__ __forceinline__ float fast_snake(float h, float rcp_aa, float aa)
{
    const float s = __sinf(aa * h);
    return h + s * s * rcp_aa;
}

__device__ __forceinline__ float dot4(float4 a, float4 b, float acc)
{
    return fmaf(a.x, b.x, fmaf(a.y, b.y, fmaf(a.z, b.z, fmaf(a.w, b.w, acc))));
}

// pack f32 -> (f16 hi, f16 lo) in one u32 (hi in low 16 bits)
__device__ __forceinline__ unsigned packhl(float v)
{
    const _Float16 h = (_Float16)v;
    const _Float16 l = (_Float16)(v - (float)h);
    f16x2 p; p[0] = h; p[1] = l;
    return __builtin_bit_cast(unsigned, p);
}

// from 8 packed u32 (ascending k) build hi-f16x8 and lo-f16x8 via v_perm
__device__ __forceinline__ void unpack8(const unsigned* u, f16x8& ah, f16x8& al)
{
    union { unsigned w[4]; f16x8 v; } H, L;
    #pragma unroll
    for (int j = 0; j < 4; ++j) {
        H.w[j] = __builtin_amdgcn_perm(u[2*j+1], u[2*j], 0x05040100u);
        L.w[j] = __builtin_amdgcn_perm(u[2*j+1], u[2*j], 0x07060302u);
    }
    ah = H.v; al = L.v;
}

// async global->LDS, 16B per lane (dest linear in lane, proven r6-r12 pattern)
__device__ __forceinline__ void gload_lds16(const void* g, void* l)
{
    __builtin_amdgcn_global_load_lds(
        (const __attribute__((address_space(1))) void*)g,
        (__attribute__((address_space(3))) void*)l, 16, 0, 0);
}

// ---------------------------------------------------------------------------
// K1 (grid 8): work-split across blocks:
//   all blocks: own pw slice (2048 elems) -> hi/lo planes
//   block 0: twiddle tables (fast __sincosf); block 1: w0/w1; block 2: softmax
// ---------------------------------------------------------------------------
__global__ __launch_bounds__(1024) void k_pre(
    const float* __restrict__ agg, const float* __restrict__ pw,
    const float* __restrict__ w0g, const float* __restrict__ w1g,
    float* __restrict__ ws)
{
    __shared__ float red[1024];
    const int t   = threadIdx.x;
    const int blk = blockIdx.x;

    _Float16* pwHi = (_Float16*)(ws + WS_PWHI);
    _Float16* pwLo = (_Float16*)(ws + WS_PWLO);
    #pragma unroll
    for (int e = 0; e < 2; ++e) {
        const int id = blk * 2048 + e * 1024 + t;   // 0..16383
        const float v = pw[id];
        const _Float16 h = (_Float16)v;
        pwHi[id] = h;
        pwLo[id] = (_Float16)(v - (float)h);
    }

    if (blk == 0) {
        _Float16* twHi = (_Float16*)(ws + WS_TWHI);
        _Float16* twLo = (_Float16*)(ws + WS_TWLO);
        #pragma unroll
        for (int e = 0; e < 4; ++e) {
            const int id = t * 4 + e;          // 0..4095
            const int n = id >> 6, k = id & 63;
            const int f = n & 31;
            float s, c;
            __sincosf(0.0981747704246810387f * (float)((k * f) & 63), &s, &c);
            const float v = (n < 32) ? c : -s;
            const _Float16 h = (_Float16)v;
            twHi[id] = h;
            twLo[id] = (_Float16)(v - (float)h);
        }
    } else if (blk == 1) {
        _Float16* w0Hi = (_Float16*)(ws + WS_W0HI);
        _Float16* w0Lo = (_Float16*)(ws + WS_W0LO);
        _Float16* w1Hi = (_Float16*)(ws + WS_W1HI);
        _Float16* w1Lo = (_Float16*)(ws + WS_W1LO);
        #pragma unroll
        for (int e = 0; e < 2; ++e) {
            const int id = e * 1024 + t;       // 0..2047
            const float v0 = w0g[id];
            const _Float16 h0 = (_Float16)v0;
            w0Hi[id] = h0;
            w0Lo[id] = (_Float16)(v0 - (float)h0);
            const float v1 = w1g[id];
            const _Float16 h1 = (_Float16)v1;
            w1Hi[id] = h1;
            w1Lo[id] = (_Float16)(v1 - (float)h1);
        }
    } else if (blk == 2) {
        float m = -1e30f;
        for (int i = t; i < W_; i += 1024) m = fmaxf(m, agg[i]);
        red[t] = m;
        __syncthreads();
        for (int s = 512; s > 0; s >>= 1) {
            if (t < s) red[t] = fmaxf(red[t], red[t + s]);
            __syncthreads();
        }
        const float mx = red[0];
        __syncthreads();
        float sum = 0.f;
        for (int i = t; i < W_; i += 1024) sum += __expf(agg[i] - mx);
        red[t] = sum;
        __syncthreads();
        for (int s = 512; s > 0; s >>= 1) {
            if (t < s) red[t] += red[t + s];
            __syncthreads();
        }
        if (t == 0) { ws[0] = mx; ws[1] = red[0]; }
    }
}

// ---------------------------------------------------------------------------
// K2 (r12 structure, reverted from r13's spilling prefetch):
// DFT-MFMA -> mag/ph (pass-0 pw async-staged to LDS underneath) ->
// proj GEMM (pass0 B from LDS, pass1 B global) -> MFMA h0/h1 -> fused out.
// 1024 thr, ~67 KB LDS -> 2 blocks/CU.
// ---------------------------------------------------------------------------
__global__ __launch_bounds__(1024, 8) void k_main(
    const float* __restrict__ x,  const float* __restrict__ pw,
    const float* __restrict__ pb, const float* __restrict__ w0g,
    const float* __restrict__ b0g,const float* __restrict__ a0g,
    const float* __restrict__ w1g,const float* __restrict__ b1g,
    const float* __restrict__ a1g,const float* __restrict__ wog,
    const float* __restrict__ bog,const float* __restrict__ agg,
    const float* __restrict__ wsp, float* __restrict__ partial)
{
    __shared__ __align__(16) _Float16 featP[16384];    // 32768 B
    __shared__ __align__(16) _Float16 arena2[16384];   // 32768 B
    __shared__ float smalls[260];
    // total ~67 KB -> 2 blocks/CU

    _Float16* featHi = featP;               // [32][256]
    _Float16* featLo = featP + 8192;
    // arena2 phase 1: twiddle planes + packed xtile; phase 2: pass-0 pw planes
    _Float16* twHiL  = arena2;              // [64][64] swizzled granules
    _Float16* twLoL  = arena2 + 4096;
    unsigned* xtileP = (unsigned*)(arena2 + 8192);  // [8][100] packed hi|lo
    _Float16* pw0Hi  = arena2;              // [32][256] swizzled (after DFT)
    _Float16* pw0Lo  = arena2 + 8192;
    // overlays inside featP (disjoint live ranges, barriers between):
    float*    pacc   = (float*)featP;       // [4][32][33] = 4224 f, bytes [0..16896)
    _Float16* projHi = featP + 8448;        // [32][40], bytes [16896..19456)
    _Float16* projLo = featP + 8448 + 1280; // bytes [19456..22016)
    _Float16* h0Hi   = featP + 11008;       // [32][72], bytes [22016..26624)
    _Float16* h0Lo   = featP + 11008 + 2304;// bytes [26624..31232)
    float*    h1L    = (float*)featP;       // [32][36], bytes [0..4608) after pacc dead

    const int t     = threadIdx.x;
    const int chunk = blockIdx.x;
    const int b     = blockIdx.y;
    const int w0c   = chunk * CH_;
    const int wid   = t >> 6;
    const int lane  = t & 63;
    const int m16   = lane & 15;
    const int kl    = lane >> 4;
    const int cdft  = wid >> 1;             // DFT channel 0..7

    // ---- async twiddle -> LDS (pre-swizzled source, r8-r12 pattern) ----
    {
        const int gl = (wid & 7) * 64 + lane;      // granule 0..511
        const int n  = gl >> 3, q = gl & 7;
        const int srcg = n * 8 + (q ^ (n & 7));
        const float* srcbase = wsp + ((wid < 8) ? WS_TWHI : WS_TWLO);
        _Float16* dst = ((wid < 8) ? twHiL : twLoL) + gl * 8;
        gload_lds16((const char*)srcbase + srcg * 16, dst);
    }

    // ---- stage x tile (packed), smalls ----
    if (t < C_ * 96) {
        const int c = t / 96;
        const int j = t - c * 96;
        int gi = w0c + j; if (gi > T_ - 1) gi = T_ - 1;
        xtileP[c * 100 + j] = packhl(x[((size_t)b * C_ + c) * T_ + gi]);
    }
    if (t < 257) {
        float smv;
        if      (t <  32) smv = pb[t];
        else if (t <  96) smv = b0g[t - 32];
        else if (t < 160) smv = a0g[t - 96];
        else if (t < 192) smv = b1g[t - 160];
        else if (t < 224) smv = a1g[t - 192];
        else if (t < 256) smv = wog[t - 224];
        else              smv = bog[0];
        smalls[t] = smv;
    }
    __syncthreads();   // xtile/smalls ready; twiddle drained (barrier=vmcnt0)

    // ---- DFT-MFMA: A built in-reg from xtileP (perm), B twiddle planes ----
    f32x4 dacc0 = {0.f,0.f,0.f,0.f}, dacc1 = {0.f,0.f,0.f,0.f};
    f32x4 dacc2 = {0.f,0.f,0.f,0.f}, dacc3 = {0.f,0.f,0.f,0.f};
    const int wra = (wid & 1) * 16 + m16;   // A-row's window index w
    {
        #pragma unroll
        for (int kstep = 0; kstep < 2; ++kstep) {
            const int kq = kstep * 4 + kl;
            unsigned ut[8];
            #pragma unroll
            for (int j = 0; j < 8; ++j) ut[j] = xtileP[cdft * 100 + wra + kq * 8 + j];
            f16x8 ah, al; unpack8(ut, ah, al);
            f32x4* dp[4] = { &dacc0, &dacc1, &dacc2, &dacc3 };
            #pragma unroll
            for (int nt = 0; nt < 4; ++nt) {
                const int nrow = nt * 16 + m16;
                const int gB = (nrow * 8 + (kq ^ (nrow & 7))) * 8;
                const f16x8 bh = *(const f16x8*)&twHiL[gB];
                const f16x8 bl = *(const f16x8*)&twLoL[gB];
                f32x4 a = *dp[nt];
                a = __builtin_amdgcn_mfma_f32_16x16x32_f16(ah, bh, a, 0, 0, 0);
                a = __builtin_amdgcn_mfma_f32_16x16x32_f16(al, bh, a, 0, 0, 0);
                a = __builtin_amdgcn_mfma_f32_16x16x32_f16(ah, bl, a, 0, 0, 0);
                *dp[nt] = a;
            }
        }
    }
    __syncthreads();   // twiddle/xtile reads complete -> arena2 reusable

    // ---- issue pass-0 pw planes -> arena2 (async; latency hides under mag/ph)
    {
        const char* pwbytes = (const char*)wsp;
        #pragma unroll
        for (int r = 0; r < 2; ++r) {
            const int gw = (r * 16 + wid) * 64;    // wave-uniform granule base
            const int g  = gw + lane;              // dest linear in lane
            const int plane = g >> 10;
            const int gp = g & 1023;
            const int o  = gp >> 5;
            const int q  = gp & 31;
            const size_t srcoff = (size_t)(plane ? WS_PWLO : WS_PWHI) * 4
                                + (size_t)o * 1024 + (size_t)((q ^ (o & 7)) * 16);
            gload_lds16(pwbytes + srcoff, (char*)arena2 + (size_t)g * 16);
        }
    }

    // ---- mag/ph (all waves); waves 0-7 write feat planes (c0-3), 8-15 hold --
    unsigned heldHi[2][4], heldLo[2][4];
    {
        const int wbase = (wid & 1) * 16 + kl * 4;
        const int ccl   = cdft & 3;
        const float reA[2][4] = {{dacc0[0],dacc0[1],dacc0[2],dacc0[3]},
                                 {dacc1[0],dacc1[1],dacc1[2],dacc1[3]}};
        const float imA[2][4] = {{dacc2[0],dacc2[1],dacc2[2],dacc2[3]},
                                 {dacc3[0],dacc3[1],dacc3[2],dacc3[3]}};
        #pragma unroll
        for (int fi = 0; fi < 2; ++fi) {
            const int f = fi * 16 + m16;
            const int g = ccl * 8 + (f >> 2);
            const int sub = 2 * (f & 3);
            #pragma unroll
            for (int r = 0; r < 4; ++r) {
                const int w  = wbase + r;
                const float re = reA[fi][r], im = imA[fi][r];
                const float mag = __logf(1.0f + __builtin_amdgcn_sqrtf(re*re + im*im));
                const float ph  = fast_atan2pi(im, re);
                const _Float16 mh = (_Float16)mag;
                const _Float16 qh = (_Float16)ph;
                f16x2 vh; vh[0] = mh; vh[1] = qh;
                f16x2 vl;
                vl[0] = (_Float16)(mag - (float)mh);
                vl[1] = (_Float16)(ph  - (float)qh);
                if (wid < 8) {
                    const int off = w * 256 + ((g ^ (w & 7)) * 8) + sub;
                    *(f16x2*)&featHi[off] = vh;
                    *(f16x2*)&featLo[off] = vl;
                } else {
                    heldHi[fi][r] = __builtin_bit_cast(unsigned, vh);
                    heldLo[fi][r] = __builtin_bit_cast(unsigned, vl);
                }
            }
        }
    }
    __syncthreads();   // feat pass-0 ready; pw0 planes drained (vmcnt0)

    // ---- proj GEMM: K-split 2; pass0 B from LDS, pass1 B from global ----
    const _Float16* pwHi = (const _Float16*)(wsp + WS_PWHI);
    const _Float16* pwLo = (const _Float16*)(wsp + WS_PWLO);
    {
        const int wt = (wid >> 1) & 1;
        const int ot = wid & 1;
        const int kq4 = wid >> 2;
        const int arow = wt * 16 + m16;
        const int brow = ot * 16 + m16;
        f32x4 acc = {0.f, 0.f, 0.f, 0.f};
        #pragma unroll
        for (int p = 0; p < 2; ++p) {
            #pragma unroll
            for (int kstep = 0; kstep < 2; ++kstep) {
                const int kp = kq4 * 64 + kstep * 32 + kl * 8;   // local k'
                f16x8 bh, bl;
                if (p == 0) {
                    const int offB = brow * 256 + (((kp >> 3) ^ (brow & 7)) * 8);
                    bh = *(const f16x8*)&pw0Hi[offB];
                    bl = *(const f16x8*)&pw0Lo[offB];
                } else {
                    bh = *(const f16x8*)&pwHi[(size_t)brow * 512 + 256 + kp];
                    bl = *(const f16x8*)&pwLo[(size_t)brow * 512 + 256 + kp];
                }
                const int g0 = kp >> 3;
                const int offA = arow * 256 + ((g0 ^ (arow & 7)) * 8);
                const f16x8 ah = *(const f16x8*)&featHi[offA];
                const f16x8 al = *(const f16x8*)&featLo[offA];
                acc = __builtin_amdgcn_mfma_f32_16x16x32_f16(ah, bh, acc, 0, 0, 0);
                acc = __builtin_amdgcn_mfma_f32_16x16x32_f16(al, bh, acc, 0, 0, 0);
                acc = __builtin_amdgcn_mfma_f32_16x16x32_f16(ah, bl, acc, 0, 0, 0);
            }
            if (p == 0) {
                __syncthreads();      // pass-0 feat reads done
                if (wid >= 8) {       // waves 8-15: write c4-7 features
                    const int wbase = (wid & 1) * 16 + kl * 4;
                    const int ccl   = cdft & 3;
                    #pragma unroll
                    for (int fi = 0; fi < 2; ++fi) {
                        const int f = fi * 16 + m16;
                        const int g = ccl * 8 + (f >> 2);
                        const int sub = 2 * (f & 3);
                        #pragma unroll
                        for (int r = 0; r < 4; ++r) {
                            const int w  = wbase + r;
                            const int off = w * 256 + ((g ^ (w & 7)) * 8) + sub;
                            *(unsigned*)&featHi[off] = heldHi[fi][r];
                            *(unsigned*)&featLo[off] = heldLo[fi][r];
                        }
                    }
                }
                __syncthreads();
            }
        }
        __syncthreads();   // pass-1 feat reads done; region free for pacc
        #pragma unroll
        for (int r = 0; r < 4; ++r) {
            const int w = wt * 16 + kl * 4 + r;
            const int o = ot * 16 + m16;
            pacc[kq4 * 1056 + w * 33 + o] = acc[r];
        }
    }
    __syncthreads();

    // ---- finalize proj: reduce 4 kq partials, bias, tanh -> proj planes ----
    {
        const int o = t & 31;
        const int w = t >> 5;
        float s = smalls[o];
        #pragma unroll
        for (int q = 0; q < 4; ++q) s += pacc[q * 1056 + w * 33 + o];
        const float pr = fast_tanh(s) * PI_F;
        const _Float16 h = (_Float16)pr;
        projHi[w * 40 + o] = h;
        projLo[w * 40 + o] = (_Float16)(pr - (float)h);
    }
    __syncthreads();

    // ---- h0 = snake(proj @ w0^T + b0) via MFMA: 8 waves, 3 MFMA each ----
    const _Float16* w0Hi = (const _Float16*)(wsp + WS_W0HI);
    const _Float16* w0Lo = (const _Float16*)(wsp + WS_W0LO);
    if (wid < 8) {
        const int wt = wid & 1;
        const int ot = wid >> 1;          // 0..3
        const int arow = wt * 16 + m16;   // proj row w
        const int brow = ot * 16 + m16;   // h0 output o
        const f16x8 ah = *(const f16x8*)&projHi[arow * 40 + kl * 8];
        const f16x8 al = *(const f16x8*)&projLo[arow * 40 + kl * 8];
        const f16x8 bh = *(const f16x8*)&w0Hi[brow * 32 + kl * 8];
        const f16x8 bl = *(const f16x8*)&w0Lo[brow * 32 + kl * 8];
        f32x4 acc = {0.f, 0.f, 0.f, 0.f};
        acc = __builtin_amdgcn_mfma_f32_16x16x32_f16(ah, bh, acc, 0, 0, 0);
        acc = __builtin_amdgcn_mfma_f32_16x16x32_f16(al, bh, acc, 0, 0, 0);
        acc = __builtin_amdgcn_mfma_f32_16x16x32_f16(ah, bl, acc, 0, 0, 0);
        const int o  = ot * 16 + m16;
        const float b0v = smalls[32 + o];
        const float aa  = fabsf(smalls[96 + o]) + 1e-8f;
        const float ra  = fast_rcp(aa);
        #pragma unroll
        for (int r = 0; r < 4; ++r) {
            const int w = wt * 16 + kl * 4 + r;
            const float hv = fast_snake(acc[r] + b0v, ra, aa);
            const _Float16 h = (_Float16)hv;
            h0Hi[w * 72 + o] = h;
            h0Lo[w * 72 + o] = (_Float16)(hv - (float)h);
        }
    }
    __syncthreads();

    // ---- h1 = snake(h0 @ w1^T + b1) via MFMA: 4 waves, 6 MFMA each ----
    const _Float16* w1Hi = (const _Float16*)(wsp + WS_W1HI);
    const _Float16* w1Lo = (const _Float16*)(wsp + WS_W1LO);
    if (wid < 4) {
        const int wt = wid & 1;
        const int ot = wid >> 1;          // 0..1
        const int arow = wt * 16 + m16;   // h0 row w
        const int brow = ot * 16 + m16;   // h1 output o
        f32x4 acc = {0.f, 0.f, 0.f, 0.f};
        #pragma unroll
        for (int ks = 0; ks < 2; ++ks) {
            const f16x8 ah = *(const f16x8*)&h0Hi[arow * 72 + ks * 32 + kl * 8];
            const f16x8 al = *(const f16x8*)&h0Lo[arow * 72 + ks * 32 + kl * 8];
            const f16x8 bh = *(const f16x8*)&w1Hi[brow * 64 + ks * 32 + kl * 8];
            const f16x8 bl = *(const f16x8*)&w1Lo[brow * 64 + ks * 32 + kl * 8];
            acc = __builtin_amdgcn_mfma_f32_16x16x32_f16(ah, bh, acc, 0, 0, 0);
            acc = __builtin_amdgcn_mfma_f32_16x16x32_f16(al, bh, acc, 0, 0, 0);
            acc = __builtin_amdgcn_mfma_f32_16x16x32_f16(ah, bl, acc, 0, 0, 0);
        }
        const int o  = ot * 16 + m16;
        const float b1v = smalls[160 + o];
        const float aa  = fabsf(smalls[192 + o]) + 1e-8f;
        const float ra  = fast_rcp(aa);
        #pragma unroll
        for (int r = 0; r < 4; ++r) {
            const int w = wt * 16 + kl * 4 + r;
            h1L[w * 36 + o] = fast_snake(acc[r] + b1v, ra, aa);
        }
    }
    __syncthreads();

    // ---- out_t + softmax weight + in-wave reduce (lanes 0-31 of wave 0) ----
    if (t < CH_) {
        const int w = t;
        float acc = 0.f;
        #pragma unroll
        for (int q = 0; q < 8; ++q)
            acc = dot4(*(const float4*)&h1L[w * 36 + q * 4],
                       *(const float4*)&smalls[224 + q * 4], acc);
        const float val = acc + smalls[256];
        const int wg = w0c + w;
        const float sw = (wg < W_) ? __expf(agg[wg] - wsp[0]) / wsp[1] : 0.f;
        float vs = val * sw;
        vs += __shfl_down(vs, 16);
        vs += __shfl_down(vs, 8);
        vs += __shfl_down(vs, 4);
        vs += __shfl_down(vs, 2);
        vs += __shfl_down(vs, 1);
        if (t == 0) partial[(size_t)chunk * B_ + b] = vs;
    }
}

// ---------------------------------------------------------------------------
// K3: final reduce over chunks -> d_out[b]. 1024 thr: 16 lanes per b.
// ---------------------------------------------------------------------------
__global__ __launch_bounds__(1024) void k_reduce(
    const float* __restrict__ partial, float* __restrict__ out)
{
    const int t = threadIdx.x;
    const int b = t >> 4;
    const int j = t & 15;
    float s = 0.f;
    #pragma unroll
    for (int q = 0; q < 4; ++q) {
        const int c = j + q * 16;
        if (c < NCHUNK_) s += partial[(size_t)c * B_ + b];
    }
    s += __shfl_xor(s, 8, 16);
    s += __shfl_xor(s, 4, 16);
    s += __shfl_xor(s, 2, 16);
    s += __shfl_xor(s, 1, 16);
    if (j == 0) out[b] = s;
}

// ---------------------------------------------------------------------------
extern "C" void kernel_launch(void* const* d_in, const int* in_sizes, int n_in,
                              void* d_out, int out_size, void* d_ws, size_t ws_size,
                              hipStream_t stream)
{
    const float* x   = (const float*)d_in[0];
    const float* pw  = (const float*)d_in[1];
    const float* pb  = (const float*)d_in[2];
    const float* w0  = (const float*)d_in[3];
    const float* b0  = (const float*)d_in[4];
    const float* a0  = (const float*)d_in[5];
    const float* w1  = (const float*)d_in[6];
    const float* b1  = (const float*)d_in[7];
    const float* a1  = (const float*)d_in[8];
    const float* wo  = (const float*)d_in[9];
    const float* bo  = (const float*)d_in[10];
    const float* agg = (const float*)d_in[11];
    float* ws  = (float*)d_ws;
    float* out = (float*)d_out;

    k_pre<<<8, 1024, 0, stream>>>(agg, pw, w0, w1, ws);
    dim3 grid(NCHUNK_, B_);
    k_main<<<grid, 1024, 0, stream>>>(x, pw, pb, w0, b0, a0, w1, b1, a1, wo, bo,
                                      agg, ws, ws + WS_PARTIAL);
    k_reduce<<<1, 1024, 0, stream>>>(ws + WS_PARTIAL, out);
}

// Round 15
// 106.641 us; speedup vs baseline: 1.1253x; 1.0515x over previous
//
#include <hip/hip_runtime.h>
#include <math.h>

#define B_ 64
#define C_ 8
#define T_ 2048
#define NF_ 32
#define MLP_ 32
#define HID_ 64
#define W_ 1985
#define CH_ 32
#define NCHUNK_ 63   /* ceil(1985/32) */
#define PI_F 3.14159265358979323846f

typedef _Float16 f16x8 __attribute__((ext_vector_type(8)));
typedef _Float16 f16x2 __attribute__((ext_vector_type(2)));
typedef float    f32x4 __attribute__((ext_vector_type(4)));

// ws layout (floats):
// [0..1] stats | [64..4095] partial | [4096..6143] twHi | [6144..8191] twLo |
// [8192..16383] pwHi (16384 f16) | [16384..24575] pwLo |
// [24576..25599] w0Hi | [25600..26623] w0Lo | [26624..27647] w1Hi | [27648..28671] w1Lo
#define WS_PARTIAL 64
#define WS_TWHI    4096
#define WS_TWLO    6144
#define WS_PWHI    8192
#define WS_PWLO    16384
#define WS_W0HI    24576
#define WS_W0LO    25600
#define WS_W1HI    26624
#define WS_W1LO    27648

// ---------------- fast inline transcendentals (branchless) ----------------
__device__ __forceinline__ float fast_rcp(float x) { return __builtin_amdgcn_rcpf(x); }

__device__ __forceinline__ float fast_atan2pi(float y, float x)
{
    const float ax = fabsf(x), ay = fabsf(y);
    const float mx = fmaxf(ax, ay), mn = fminf(ax, ay);
    const float r  = mn * fast_rcp(fmaxf(mx, 1e-30f));
    const float t  = r * r;
    float a = -0.003730950f;
    a = fmaf(a, t,  0.016759940f);
    a = fmaf(a, t, -0.037059946f);
    a = fmaf(a, t,  0.061602941f);
    a = fmaf(a, t, -0.105877528f);
    a = fmaf(a, t,  0.318302656f);
    a *= r;
    a = (ay > ax) ? (0.5f - a) : a;
    a = (x < 0.0f) ? (1.0f - a) : a;
    return copysignf(a, y);
}

__device__ __forceinline__ float fast_tanh(float x)
{
    const float e = __expf(2.0f * x);
    return 1.0f - 2.0f * fast_rcp(e + 1.0f);
}

__device__ __forceinline__ float fast_snake(float h, float rcp_aa, float aa)
{
    const float s = __sinf(aa * h);
    return h + s * s * rcp_aa;
}

__device__ __forceinline__ float dot4(float4 a, float4 b, float acc)
{
    return fmaf(a.x, b.x, fmaf(a.y, b.y, fmaf(a.z, b.z, fmaf(a.w, b.w, acc))));
}

// pack f32 -> (f16 hi, f16 lo) in one u32 (hi in low 16 bits)
__device__ __forceinline__ unsigned packhl(float v)
{
    const _Float16 h = (_Float16)v;
    const _Float16 l = (_Float16)(v - (float)h);
    f16x2 p; p[0] = h; p[1] = l;
    return __builtin_bit_cast(unsigned, p);
}

// hi-plane only from 8 packed u32 (ascending k)
__device__ __forceinline__ f16x8 unpack8hi(const unsigned* u)
{
    union { unsigned w[4]; f16x8 v; } H;
    #pragma unroll
    for (int j = 0; j < 4; ++j)
        H.w[j] = __builtin_amdgcn_perm(u[2*j+1], u[2*j], 0x05040100u);
    return H.v;
}

// async global->LDS, 16B per lane (dest linear in lane, proven r6-r14 pattern)
__device__ __forceinline__ void gload_lds16(const void* g, void* l)
{
    __builtin_amdgcn_global_load_lds(
        (const __attribute__((address_space(1))) void*)g,
        (__attribute__((address_space(3))) void*)l, 16, 0, 0);
}

// ---------------------------------------------------------------------------
// K1 (grid 8): work-split across blocks:
//   all blocks: own pw slice (2048 elems) -> hi/lo planes
//   block 0: twiddle hi table (fast __sincosf); block 1: w0/w1; block 2: softmax
// ---------------------------------------------------------------------------
__global__ __launch_bounds__(1024) void k_pre(
    const float* __restrict__ agg, const float* __restrict__ pw,
    const float* __restrict__ w0g, const float* __restrict__ w1g,
    float* __restrict__ ws)
{
    __shared__ float red[1024];
    const int t   = threadIdx.x;
    const int blk = blockIdx.x;

    _Float16* pwHi = (_Float16*)(ws + WS_PWHI);
    _Float16* pwLo = (_Float16*)(ws + WS_PWLO);
    #pragma unroll
    for (int e = 0; e < 2; ++e) {
        const int id = blk * 2048 + e * 1024 + t;   // 0..16383
        const float v = pw[id];
        const _Float16 h = (_Float16)v;
        pwHi[id] = h;
        pwLo[id] = (_Float16)(v - (float)h);
    }

    if (blk == 0) {
        _Float16* twHi = (_Float16*)(ws + WS_TWHI);
        #pragma unroll
        for (int e = 0; e < 4; ++e) {
            const int id = t * 4 + e;          // 0..4095
            const int n = id >> 6, k = id & 63;
            const int f = n & 31;
            float s, c;
            __sincosf(0.0981747704246810387f * (float)((k * f) & 63), &s, &c);
            const float v = (n < 32) ? c : -s;
            twHi[id] = (_Float16)v;
        }
    } else if (blk == 1) {
        _Float16* w0Hi = (_Float16*)(ws + WS_W0HI);
        _Float16* w0Lo = (_Float16*)(ws + WS_W0LO);
        _Float16* w1Hi = (_Float16*)(ws + WS_W1HI);
        _Float16* w1Lo = (_Float16*)(ws + WS_W1LO);
        #pragma unroll
        for (int e = 0; e < 2; ++e) {
            const int id = e * 1024 + t;       // 0..2047
            const float v0 = w0g[id];
            const _Float16 h0 = (_Float16)v0;
            w0Hi[id] = h0;
            w0Lo[id] = (_Float16)(v0 - (float)h0);
            const float v1 = w1g[id];
            const _Float16 h1 = (_Float16)v1;
            w1Hi[id] = h1;
            w1Lo[id] = (_Float16)(v1 - (float)h1);
        }
    } else if (blk == 2) {
        float m = -1e30f;
        for (int i = t; i < W_; i += 1024) m = fmaxf(m, agg[i]);
        red[t] = m;
        __syncthreads();
        for (int s = 512; s > 0; s >>= 1) {
            if (t < s) red[t] = fmaxf(red[t], red[t + s]);
            __syncthreads();
        }
        const float mx = red[0];
        __syncthreads();
        float sum = 0.f;
        for (int i = t; i < W_; i += 1024) sum += __expf(agg[i] - mx);
        red[t] = sum;
        __syncthreads();
        for (int s = 512; s > 0; s >>= 1) {
            if (t < s) red[t] += red[t + s];
            __syncthreads();
        }
        if (t == 0) { ws[0] = mx; ws[1] = red[0]; }
    }
}

// ---------------------------------------------------------------------------
// K2 (r14 structure; DFT trimmed to pure-fp16 inputs, 1 MFMA per n-tile):
// DFT-MFMA -> mag/ph (pass-0 pw async-staged to LDS underneath) ->
// proj GEMM 3-pass (pass0 B from LDS, pass1 B global) -> MFMA h0/h1 -> out.
// 1024 thr, ~67 KB LDS -> 2 blocks/CU.
// ---------------------------------------------------------------------------
__global__ __launch_bounds__(1024, 8) void k_main(
    const float* __restrict__ x,  const float* __restrict__ pw,
    const float* __restrict__ pb, const float* __restrict__ w0g,
    const float* __restrict__ b0g,const float* __restrict__ a0g,
    const float* __restrict__ w1g,const float* __restrict__ b1g,
    const float* __restrict__ a1g,const float* __restrict__ wog,
    const float* __restrict__ bog,const float* __restrict__ agg,
    const float* __restrict__ wsp, float* __restrict__ partial)
{
    __shared__ __align__(16) _Float16 featP[16384];    // 32768 B
    __shared__ __align__(16) _Float16 arena2[16384];   // 32768 B
    __shared__ float smalls[260];
    // total ~67 KB -> 2 blocks/CU

    _Float16* featHi = featP;               // [32][256]
    _Float16* featLo = featP + 8192;
    // arena2 phase 1: twiddle hi plane + packed xtile; phase 2: pass-0 pw planes
    _Float16* twHiL  = arena2;              // [64][64] swizzled granules (8 KB)
    unsigned* xtileP = (unsigned*)(arena2 + 8192);  // [8][100] packed hi|lo
    _Float16* pw0Hi  = arena2;              // [32][256] swizzled (after DFT)
    _Float16* pw0Lo  = arena2 + 8192;
    // overlays inside featP (disjoint live ranges, barriers between):
    float*    pacc   = (float*)featP;       // [4][32][33] = 4224 f, bytes [0..16896)
    _Float16* projHi = featP + 8448;        // [32][40], bytes [16896..19456)
    _Float16* projLo = featP + 8448 + 1280; // bytes [19456..22016)
    _Float16* h0Hi   = featP + 11008;       // [32][72], bytes [22016..26624)
    _Float16* h0Lo   = featP + 11008 + 2304;// bytes [26624..31232)
    float*    h1L    = (float*)featP;       // [32][36], bytes [0..4608) after pacc dead

    const int t     = threadIdx.x;
    const int chunk = blockIdx.x;
    const int b     = blockIdx.y;
    const int w0c   = chunk * CH_;
    const int wid   = t >> 6;
    const int lane  = t & 63;
    const int m16   = lane & 15;
    const int kl    = lane >> 4;
    const int cdft  = wid >> 1;             // DFT channel 0..7

    // ---- async twiddle-hi -> LDS (pre-swizzled source); waves 0-7 only ----
    if (wid < 8) {
        const int gl = wid * 64 + lane;            // granule 0..511
        const int n  = gl >> 3, q = gl & 7;
        const int srcg = n * 8 + (q ^ (n & 7));
        gload_lds16((const char*)(wsp + WS_TWHI) + srcg * 16, twHiL + gl * 8);
    }

    // ---- stage x tile (packed), smalls ----
    if (t < C_ * 96) {
        const int c = t / 96;
        const int j = t - c * 96;
        int gi = w0c + j; if (gi > T_ - 1) gi = T_ - 1;
        xtileP[c * 100 + j] = packhl(x[((size_t)b * C_ + c) * T_ + gi]);
    }
    if (t < 257) {
        float smv;
        if      (t <  32) smv = pb[t];
        else if (t <  96) smv = b0g[t - 32];
        else if (t < 160) smv = a0g[t - 96];
        else if (t < 192) smv = b1g[t - 160];
        else if (t < 224) smv = a1g[t - 192];
        else if (t < 256) smv = wog[t - 224];
        else              smv = bog[0];
        smalls[t] = smv;
    }
    __syncthreads();   // xtile/smalls ready; twiddle drained (barrier=vmcnt0)

    // ---- DFT-MFMA: pure-fp16 inputs (exact products, fp32 accumulate) ----
    f32x4 dacc0 = {0.f,0.f,0.f,0.f}, dacc1 = {0.f,0.f,0.f,0.f};
    f32x4 dacc2 = {0.f,0.f,0.f,0.f}, dacc3 = {0.f,0.f,0.f,0.f};
    const int wra = (wid & 1) * 16 + m16;   // A-row's window index w
    {
        #pragma unroll
        for (int kstep = 0; kstep < 2; ++kstep) {
            const int kq = kstep * 4 + kl;
            unsigned ut[8];
            #pragma unroll
            for (int j = 0; j < 8; ++j) ut[j] = xtileP[cdft * 100 + wra + kq * 8 + j];
            const f16x8 ah = unpack8hi(ut);
            f32x4* dp[4] = { &dacc0, &dacc1, &dacc2, &dacc3 };
            #pragma unroll
            for (int nt = 0; nt < 4; ++nt) {
                const int nrow = nt * 16 + m16;
                const int gB = (nrow * 8 + (kq ^ (nrow & 7))) * 8;
                const f16x8 bh = *(const f16x8*)&twHiL[gB];
                *dp[nt] = __builtin_amdgcn_mfma_f32_16x16x32_f16(ah, bh, *dp[nt], 0, 0, 0);
            }
        }
    }
    __syncthreads();   // twiddle/xtile reads complete -> arena2 reusable

    // ---- issue pass-0 pw planes -> arena2 (async; latency hides under mag/ph)
    {
        const char* pwbytes = (const char*)wsp;
        #pragma unroll
        for (int r = 0; r < 2; ++r) {
            const int gw = (r * 16 + wid) * 64;    // wave-uniform granule base
            const int g  = gw + lane;              // dest linear in lane
            const int plane = g >> 10;
            const int gp = g & 1023;
            const int o  = gp >> 5;
            const int q  = gp & 31;
            const size_t srcoff = (size_t)(plane ? WS_PWLO : WS_PWHI) * 4
                                + (size_t)o * 1024 + (size_t)((q ^ (o & 7)) * 16);
            gload_lds16(pwbytes + srcoff, (char*)arena2 + (size_t)g * 16);
        }
    }

    // ---- mag/ph (all waves); waves 0-7 write feat planes (c0-3), 8-15 hold --
    unsigned heldHi[2][4], heldLo[2][4];
    {
        const int wbase = (wid & 1) * 16 + kl * 4;
        const int ccl   = cdft & 3;
        const float reA[2][4] = {{dacc0[0],dacc0[1],dacc0[2],dacc0[3]},
                                 {dacc1[0],dacc1[1],dacc1[2],dacc1[3]}};
        const float imA[2][4] = {{dacc2[0],dacc2[1],dacc2[2],dacc2[3]},
                                 {dacc3[0],dacc3[1],dacc3[2],dacc3[3]}};
        #pragma unroll
        for (int fi = 0; fi < 2; ++fi) {
            const int f = fi * 16 + m16;
            const int g = ccl * 8 + (f >> 2);
            const int sub = 2 * (f & 3);
            #pragma unroll
            for (int r = 0; r < 4; ++r) {
                const int w  = wbase + r;
                const float re = reA[fi][r], im = imA[fi][r];
                const float mag = __logf(1.0f + __builtin_amdgcn_sqrtf(re*re + im*im));
                const float ph  = fast_atan2pi(im, re);
                const _Float16 mh = (_Float16)mag;
                const _Float16 qh = (_Float16)ph;
                f16x2 vh; vh[0] = mh; vh[1] = qh;
                f16x2 vl;
                vl[0] = (_Float16)(mag - (float)mh);
                vl[1] = (_Float16)(ph  - (float)qh);
                if (wid < 8) {
                    const int off = w * 256 + ((g ^ (w & 7)) * 8) + sub;
                    *(f16x2*)&featHi[off] = vh;
                    *(f16x2*)&featLo[off] = vl;
                } else {
                    heldHi[fi][r] = __builtin_bit_cast(unsigned, vh);
                    heldLo[fi][r] = __builtin_bit_cast(unsigned, vl);
                }
            }
        }
    }
    __syncthreads();   // feat pass-0 ready; pw0 planes drained (vmcnt0)

    // ---- proj GEMM: K-split 2; pass0 B from LDS, pass1 B from global ----
    const _Float16* pwHi = (const _Float16*)(wsp + WS_PWHI);
    const _Float16* pwLo = (const _Float16*)(wsp + WS_PWLO);
    {
        const int wt = (wid >> 1) & 1;
        const int ot = wid & 1;
        const int kq4 = wid >> 2;
        const int arow = wt * 16 + m16;
        const int brow = ot * 16 + m16;
        f32x4 acc = {0.f, 0.f, 0.f, 0.f};
        #pragma unroll
        for (int p = 0; p < 2; ++p) {
            #pragma unroll
            for (int kstep = 0; kstep < 2; ++kstep) {
                const int kp = kq4 * 64 + kstep * 32 + kl * 8;   // local k'
                f16x8 bh, bl;
                if (p == 0) {
                    const int offB = brow * 256 + (((kp >> 3) ^ (brow & 7)) * 8);
                    bh = *(const f16x8*)&pw0Hi[offB];
                    bl = *(const f16x8*)&pw0Lo[offB];
                } else {
                    bh = *(const f16x8*)&pwHi[(size_t)brow * 512 + 256 + kp];
                    bl = *(const f16x8*)&pwLo[(size_t)brow * 512 + 256 + kp];
                }
                const int g0 = kp >> 3;
                const int offA = arow * 256 + ((g0 ^ (arow & 7)) * 8);
                const f16x8 ah = *(const f16x8*)&featHi[offA];
                const f16x8 al = *(const f16x8*)&featLo[offA];
                acc = __builtin_amdgcn_mfma_f32_16x16x32_f16(ah, bh, acc, 0, 0, 0);
                acc = __builtin_amdgcn_mfma_f32_16x16x32_f16(al, bh, acc, 0, 0, 0);
                acc = __builtin_amdgcn_mfma_f32_16x16x32_f16(ah, bl, acc, 0, 0, 0);
            }
            if (p == 0) {
                __syncthreads();      // pass-0 feat reads done
                if (wid >= 8) {       // waves 8-15: write c4-7 features
                    const int wbase = (wid & 1) * 16 + kl * 4;
                    const int ccl   = cdft & 3;
                    #pragma unroll
                    for (int fi = 0; fi < 2; ++fi) {
                        const int f = fi * 16 + m16;
                        const int g = ccl * 8 + (f >> 2);
                        const int sub = 2 * (f & 3);
                        #pragma unroll
                        for (int r = 0; r < 4; ++r) {
                            const int w  = wbase + r;
                            const int off = w * 256 + ((g ^ (w & 7)) * 8) + sub;
                            *(unsigned*)&featHi[off] = heldHi[fi][r];
                            *(unsigned*)&featLo[off] = heldLo[fi][r];
                        }
                    }
                }
                __syncthreads();
            }
        }
        __syncthreads();   // pass-1 feat reads done; region free for pacc
        #pragma unroll
        for (int r = 0; r < 4; ++r) {
            const int w = wt * 16 + kl * 4 + r;
            const int o = ot * 16 + m16;
            pacc[kq4 * 1056 + w * 33 + o] = acc[r];
        }
    }
    __syncthreads();

    // ---- finalize proj: reduce 4 kq partials, bias, tanh -> proj planes ----
    {
        const int o = t & 31;
        const int w = t >> 5;
        float s = smalls[o];
        #pragma unroll
        for (int q = 0; q < 4; ++q) s += pacc[q * 1056 + w * 33 + o];
        const float pr = fast_tanh(s) * PI_F;
        const _Float16 h = (_Float16)pr;
        projHi[w * 40 + o] = h;
        projLo[w * 40 + o] = (_Float16)(pr - (float)h);
    }
    __syncthreads();

    // ---- h0 = snake(proj @ w0^T + b0) via MFMA: 8 waves, 3 MFMA each ----
    const _Float16* w0Hi = (const _Float16*)(wsp + WS_W0HI);
    const _Float16* w0Lo = (const _Float16*)(wsp + WS_W0LO);
    if (wid < 8) {
        const int wt = wid & 1;
        const int ot = wid >> 1;          // 0..3
        const int arow = wt * 16 + m16;   // proj row w
        const int brow = ot * 16 + m16;   // h0 output o
        const f16x8 ah = *(const f16x8*)&projHi[arow * 40 + kl * 8];
        const f16x8 al = *(const f16x8*)&projLo[arow * 40 + kl * 8];
        const f16x8 bh = *(const f16x8*)&w0Hi[brow * 32 + kl * 8];
        const f16x8 bl = *(const f16x8*)&w0Lo[brow * 32 + kl * 8];
        f32x4 acc = {0.f, 0.f, 0.f, 0.f};
        acc = __builtin_amdgcn_mfma_f32_16x16x32_f16(ah, bh, acc, 0, 0, 0);
        acc = __builtin_amdgcn_mfma_f32_16x16x32_f16(al, bh, acc, 0, 0, 0);
        acc = __builtin_amdgcn_mfma_f32_16x16x32_f16(ah, bl, acc, 0, 0, 0);
        const int o  = ot * 16 + m16;
        const float b0v = smalls[32 + o];
        const float aa  = fabsf(smalls[96 + o]) + 1e-8f;
        const float ra  = fast_rcp(aa);
        #pragma unroll
        for (int r = 0; r < 4; ++r) {
            const int w = wt * 16 + kl * 4 + r;
            const float hv = fast_snake(acc[r] + b0v, ra, aa);
            const _Float16 h = (_Float16)hv;
            h0Hi[w * 72 + o] = h;
            h0Lo[w * 72 + o] = (_Float16)(hv - (float)h);
        }
    }
    __syncthreads();

    // ---- h1 = snake(h0 @ w1^T + b1) via MFMA: 4 waves, 6 MFMA each ----
    const _Float16* w1Hi = (const _Float16*)(wsp + WS_W1HI);
    const _Float16* w1Lo = (const _Float16*)(wsp + WS_W1LO);
    if (wid < 4) {
        const int wt = wid & 1;
        const int ot = wid >> 1;          // 0..1
        const int arow = wt * 16 + m16;   // h0 row w
        const int brow = ot * 16 + m16;   // h1 output o
        f32x4 acc = {0.f, 0.f, 0.f, 0.f};
        #pragma unroll
        for (int ks = 0; ks < 2; ++ks) {
            const f16x8 ah = *(const f16x8*)&h0Hi[arow * 72 + ks * 32 + kl * 8];
            const f16x8 al = *(const f16x8*)&h0Lo[arow * 72 + ks * 32 + kl * 8];
            const f16x8 bh = *(const f16x8*)&w1Hi[brow * 64 + ks * 32 + kl * 8];
            const f16x8 bl = *(const f16x8*)&w1Lo[brow * 64 + ks * 32 + kl * 8];
            acc = __builtin_amdgcn_mfma_f32_16x16x32_f16(ah, bh, acc, 0, 0, 0);
            acc = __builtin_amdgcn_mfma_f32_16x16x32_f16(al, bh, acc, 0, 0, 0);
            acc = __builtin_amdgcn_mfma_f32_16x16x32_f16(ah, bl, acc, 0, 0, 0);
        }
        const int o  = ot * 16 + m16;
        const float b1v = smalls[160 + o];
        const float aa  = fabsf(smalls[192 + o]) + 1e-8f;
        const float ra  = fast_rcp(aa);
        #pragma unroll
        for (int r = 0; r < 4; ++r) {
            const int w = wt * 16 + kl * 4 + r;
            h1L[w * 36 + o] = fast_snake(acc[r] + b1v, ra, aa);
        }
    }
    __syncthreads();

    // ---- out_t + softmax weight + in-wave reduce (lanes 0-31 of wave 0) ----
    if (t < CH_) {
        const int w = t;
        float acc = 0.f;
        #pragma unroll
        for (int q = 0; q < 8; ++q)
            acc = dot4(*(const float4*)&h1L[w * 36 + q * 4],
                       *(const float4*)&smalls[224 + q * 4], acc);
        const float val = acc + smalls[256];
        const int wg = w0c + w;
        const float sw = (wg < W_) ? __expf(agg[wg] - wsp[0]) / wsp[1] : 0.f;
        float vs = val * sw;
        vs += __shfl_down(vs, 16);
        vs += __shfl_down(vs, 8);
        vs += __shfl_down(vs, 4);
        vs += __shfl_down(vs, 2);
        vs += __shfl_down(vs, 1);
        if (t == 0) partial[(size_t)chunk * B_ + b] = vs;
    }
}

// ---------------------------------------------------------------------------
// K3: final reduce over chunks -> d_out[b]. 1024 thr: 16 lanes per b.
// ---------------------------------------------------------------------------
__global__ __launch_bounds__(1024) void k_reduce(
    const float* __restrict__ partial, float* __restrict__ out)
{
    const int t = threadIdx.x;
    const int b = t >> 4;
    const int j = t & 15;
    float s = 0.f;
    #pragma unroll
    for (int q = 0; q < 4; ++q) {
        const int c = j + q * 16;
        if (c < NCHUNK_) s += partial[(size_t)c * B_ + b];
    }
    s += __shfl_xor(s, 8, 16);
    s += __shfl_xor(s, 4, 16);
    s += __shfl_xor(s, 2, 16);
    s += __shfl_xor(s, 1, 16);
    if (j == 0) out[b] = s;
}

// ---------------------------------------------------------------------------
extern "C" void kernel_launch(void* const* d_in, const int* in_sizes, int n_in,
                              void* d_out, int out_size, void* d_ws, size_t ws_size,
                              hipStream_t stream)
{
    const float* x   = (const float*)d_in[0];
    const float* pw  = (const float*)d_in[1];
    const float* pb  = (const float*)d_in[2];
    const float* w0  = (const float*)d_in[3];
    const float* b0  = (const float*)d_in[4];
    const float* a0  = (const float*)d_in[5];
    const float* w1  = (const float*)d_in[6];
    const float* b1  = (const float*)d_in[7];
    const float* a1  = (const float*)d_in[8];
    const float* wo  = (const float*)d_in[9];
    const float* bo  = (const float*)d_in[10];
    const float* agg = (const float*)d_in[11];
    float* ws  = (float*)d_ws;
    float* out = (float*)d_out;

    k_pre<<<8, 1024, 0, stream>>>(agg, pw, w0, w1, ws);
    dim3 grid(NCHUNK_, B_);
    k_main<<<grid, 1024, 0, stream>>>(x, pw, pb, w0, b0, a0, w1, b1, a1, wo, bo,
                                      agg, ws, ws + WS_PARTIAL);
    k_reduce<<<1, 1024, 0, stream>>>(ws + WS_PARTIAL, out);
}